// Round 1
// baseline (234.415 us; speedup 1.0000x reference)
//
#include <hip/hip_runtime.h>
#include <math.h>

// Problem constants
constexpr int Bn  = 2;
constexpr int Sn  = 4096;
constexpr int En  = 1024;
constexpr int Hn  = 16;
constexpr int Mtot = Bn * Sn;             // 8192
constexpr int Kp  = 1024;                 // GEMM K (fp16 single precision)
constexpr int PAD = 72;                   // LDS row stride (bf16), 144 B = 9x16B

typedef __bf16    bf16x8 __attribute__((ext_vector_type(8)));
typedef __bf16    bf16x4 __attribute__((ext_vector_type(4)));
typedef _Float16  f16x8  __attribute__((ext_vector_type(8)));
typedef _Float16  f16x4  __attribute__((ext_vector_type(4)));
typedef float     f32x4  __attribute__((ext_vector_type(4)));

// ---------------- fp32 -> fp16 conversion ----------------
__global__ void __launch_bounds__(256)
cvt_hs_kernel(const float* __restrict__ hs, _Float16* __restrict__ hs16)
{
    int t = blockIdx.x * 256 + threadIdx.x;
    int m = t >> 8;
    int k = (t & 255) << 2;
    float4 x = *(const float4*)&hs[((size_t)m << 10) + k];
    f16x4 h;
    h[0] = (_Float16)x.x; h[1] = (_Float16)x.y;
    h[2] = (_Float16)x.z; h[3] = (_Float16)x.w;
    *(f16x4*)&hs16[((size_t)m << 10) + k] = h;
}

__global__ void __launch_bounds__(256)
cvt_w_kernel(const float* __restrict__ qw, const float* __restrict__ kw,
             const float* __restrict__ vw, _Float16* __restrict__ w16)
{
    int t = blockIdx.x * 256 + threadIdx.x;
    int gn = t >> 8;
    int k  = (t & 255) << 2;
    int p  = gn >> 10, n = gn & 1023;
    const float* src = (p == 0) ? qw : (p == 1) ? kw : vw;
    float4 x = *(const float4*)&src[((size_t)n << 10) + k];
    f16x4 h;
    h[0] = (_Float16)x.x; h[1] = (_Float16)x.y;
    h[2] = (_Float16)x.z; h[3] = (_Float16)x.w;
    *(f16x4*)&w16[((size_t)gn << 10) + k] = h;
}

// ---------------- QKV projection: fp16 MFMA GEMM ----------------------------
// A = hs16 (m = seq), B = w16 (n = feature, 3072 rows = q|k|v).
// v2 changes vs r0 baseline:
//   (1) double-buffered LDS, stage k+1 issued BEFORE compute of k, ONE barrier
//       per K-step (T3-minimum pipeline) -> load latency hidden under compute
//   (2) XOR-swizzle (chunk ^= (row>>1)&3) applied on the pre-swizzled GLOBAL
//       source at staging + on the ds_read address -> bank-conflict-free reads
//   (3) q/k blocks compute with swapped MFMA operands so the accumulator's
//       row dim (quad*4+r) is the FEATURE dim -> contiguous bf16x4 stores
__device__ inline void load_lds16(const void* g, void* s) {
    __builtin_amdgcn_global_load_lds((const __attribute__((address_space(1))) void*)g,
                                     (__attribute__((address_space(3))) void*)s,
                                     16, 0, 0);
}

__global__ void __launch_bounds__(256)
qkv_mfma_kernel(const _Float16* __restrict__ A2, const _Float16* __restrict__ B2,
                const float* __restrict__ qb, const float* __restrict__ kb,
                const float* __restrict__ vb,
                __bf16* __restrict__ q16, __bf16* __restrict__ k16,
                __bf16* __restrict__ vt16)
{
    __shared__ _Float16 As[2][128 * 32];
    __shared__ _Float16 Bs[2][128 * 32];

    const int tid  = threadIdx.x;
    const int m0   = blockIdx.x * 128;     // seq tile
    const int n0   = blockIdx.y * 128;     // feature tile (0..3071)
    const int w    = tid >> 6;
    const int lane = tid & 63;
    const int wm   = w >> 1, wn = w & 1;
    const int mrow = lane & 15, quad = lane >> 4;
    const int p    = n0 >> 10;             // 0=q 1=k 2=v (uniform per block)

    // staging: row = w*16 + (lane>>2); LDS dest is linear (lane*16B), so the
    // swizzle goes into the per-lane GLOBAL chunk: c_load = (lane&3) ^ f(row),
    // f(row) = (row>>1)&3 = (lane>>3)&3
    const int stRow = w * 16 + (lane >> 2);
    const int stCol = (((lane & 3) ^ ((lane >> 3) & 3))) * 8;

    // read swizzle: LDS slot (row, c) holds global chunk c ^ ((row>>1)&3);
    // row bits 1..2 come from mrow for every fragment row
    const int rq = ((quad ^ ((mrow >> 1) & 3))) * 8;

    f32x4 acc[4][4] = {};

    const _Float16* Abase = A2 + (size_t)(m0 + stRow) * Kp + stCol;
    const _Float16* Bbase = B2 + (size_t)(n0 + stRow) * Kp + stCol;

    auto stage = [&](int k0, int buf) {
        _Float16* AsW = &As[buf][w * 512];
        _Float16* BsW = &Bs[buf][w * 512];
        load_lds16(Abase + k0,            AsW);
        load_lds16(Abase + 64 * Kp + k0,  AsW + 2048);
        load_lds16(Bbase + k0,            BsW);
        load_lds16(Bbase + 64 * Kp + k0,  BsW + 2048);
    };

    stage(0, 0);
    __syncthreads();

    for (int k0 = 0; k0 < Kp; k0 += 32) {
        const int cur = (k0 >> 5) & 1;
        if (k0 + 32 < Kp) stage(k0 + 32, cur ^ 1);   // prefetch next K-step

        f16x8 af[4], bfr[4];
        const _Float16* AsR = &As[cur][0];
        const _Float16* BsR = &Bs[cur][0];
#pragma unroll
        for (int t = 0; t < 4; t++) {
            af[t]  = *(const f16x8*)&AsR[(wm * 64 + t * 16 + mrow) * 32 + rq];
            bfr[t] = *(const f16x8*)&BsR[(wn * 64 + t * 16 + mrow) * 32 + rq];
        }
        if (p < 2) {
            // swapped operands: C[m=feature][n=seq]
#pragma unroll
            for (int ti = 0; ti < 4; ti++)
#pragma unroll
                for (int tj = 0; tj < 4; tj++)
                    acc[ti][tj] = __builtin_amdgcn_mfma_f32_16x16x32_f16(
                        bfr[tj], af[ti], acc[ti][tj], 0, 0, 0);
        } else {
            // original: C[m=seq][n=feature]
#pragma unroll
            for (int ti = 0; ti < 4; ti++)
#pragma unroll
                for (int tj = 0; tj < 4; tj++)
                    acc[ti][tj] = __builtin_amdgcn_mfma_f32_16x16x32_f16(
                        af[ti], bfr[tj], acc[ti][tj], 0, 0, 0);
        }
        __syncthreads();   // drains this iter's stage (vmcnt) + frees buf[cur]
    }

    if (p < 2) {
        // acc[ti][tj]: row (quad*4+r) = feature, col (mrow) = seq
        const float* bptr = (p == 0) ? qb : kb;
        __bf16* dst = (p == 0) ? q16 : k16;
        const float scl = (p == 0) ? 0.125f : 1.0f;
#pragma unroll
        for (int ti = 0; ti < 4; ti++) {
            const int m  = m0 + wm * 64 + ti * 16 + mrow;   // seq
            const int bb = m >> 12, ss = m & 4095;
#pragma unroll
            for (int tj = 0; tj < 4; tj++) {
                const int fl = (n0 + wn * 64 + tj * 16 + quad * 4) & 1023;
                const int hh = fl >> 6, dd = fl & 63;       // dd..dd+3
                const float4 bv = *(const float4*)&bptr[fl];
                bf16x4 o;
                o[0] = (__bf16)((acc[ti][tj][0] + bv.x) * scl);
                o[1] = (__bf16)((acc[ti][tj][1] + bv.y) * scl);
                o[2] = (__bf16)((acc[ti][tj][2] + bv.z) * scl);
                o[3] = (__bf16)((acc[ti][tj][3] + bv.w) * scl);
                *(bf16x4*)&dst[((size_t)(bb * Hn + hh) * Sn + ss) * 64 + dd] = o;
            }
        }
    } else {
        // acc[ti][tj]: row (quad*4+r) = seq, col (mrow) = feature; V^T layout
#pragma unroll
        for (int tj = 0; tj < 4; tj++) {
            const int n  = n0 + wn * 64 + tj * 16 + mrow;
            const float bv = vb[n & 1023];
            const int hh = (n & 1023) >> 6, dd = n & 63;
#pragma unroll
            for (int ti = 0; ti < 4; ti++) {
                const int m  = m0 + wm * 64 + ti * 16 + quad * 4;   // + r
                const int bb = m >> 12, ss = m & 4095;
                bf16x4 pv4;
#pragma unroll
                for (int r = 0; r < 4; r++)
                    pv4[r] = (__bf16)(acc[ti][tj][r] + bv);
                *(bf16x4*)&vt16[((size_t)(bb * Hn + hh) * 64 + dd) * Sn + ss] = pv4;
            }
        }
    }
}

// ---------------- Banded attention: MFMA, double-buffered staging -----------
// Block = 256 queries (4 waves x 64). S^T = K.Q^T ; O^T = V^T.P^T.
// ONE barrier per subtile: compute reads buf[st&1] while regs hold st+1 data;
// writes go to buf[(st+1)&1], whose last readers synced at the st-1 barrier.
__global__ void __launch_bounds__(256, 2)
banded_attn_kernel(const __bf16* __restrict__ q16, const __bf16* __restrict__ k16,
                   const __bf16* __restrict__ vt16, const int* __restrict__ mask,
                   float* __restrict__ out)
{
    __shared__ __bf16 Kt[2][64 * PAD];
    __shared__ __bf16 Vt[2][64 * PAD];
    __shared__ __bf16 Pt[4][64 * PAD];
    __shared__ float  Msh[768];

    const int c = blockIdx.x, h = blockIdx.y, b = blockIdx.z;
    const int bh = b * Hn + h;
    const int i0 = c * 256;
    const int jwin0 = i0 - 256;
    const int tid  = threadIdx.x;
    const int wv   = tid >> 6;
    const int lane = tid & 63;
    const int quad = lane >> 4, mrow = lane & 15;

#pragma unroll
    for (int rep = 0; rep < 3; rep++) {
        int idx = rep * 256 + tid;
        int jg  = jwin0 + idx;
        float mv = 0.f;
        if (jg >= 0 && jg < Sn && mask[b * Sn + jg] != 0) mv = -10000.f;
        Msh[idx] = mv;
    }

    // Q B-fragments (loop-invariant): B[k=d][n=q]
    bf16x8 qf[4][2];
    const __bf16* qbase = q16 + (((size_t)bh * Sn + i0 + wv * 64) << 6);
#pragma unroll
    for (int tjq = 0; tjq < 4; tjq++)
#pragma unroll
        for (int kc = 0; kc < 2; kc++)
            qf[tjq][kc] = *(const bf16x8*)(qbase + (16 * tjq + mrow) * 64 + 32 * kc + 8 * quad);

    const int sr = lane >> 3;      // 0..7
    const int sc = lane & 7;       // 16B chunk
    bf16x8 kreg0, kreg1, vreg0, vreg1;
    auto gload = [&](int st) {
        const int j0 = jwin0 + st * 64;
        const int r0 = wv * 16 + sr;
        const int r1 = wv * 16 + 8 + sr;
        int jk0 = j0 + r0; jk0 = jk0 < 0 ? 0 : (jk0 > Sn - 1 ? Sn - 1 : jk0);
        int jk1 = j0 + r1; jk1 = jk1 < 0 ? 0 : (jk1 > Sn - 1 ? Sn - 1 : jk1);
        kreg0 = *(const bf16x8*)&k16[(((size_t)bh * Sn + jk0) << 6) + sc * 8];
        kreg1 = *(const bf16x8*)&k16[(((size_t)bh * Sn + jk1) << 6) + sc * 8];
        int jv = j0 + sc * 8; jv = jv < 0 ? 0 : (jv > Sn - 8 ? Sn - 8 : jv);
        vreg0 = *(const bf16x8*)&vt16[((size_t)bh * 64 + r0) * Sn + jv];
        vreg1 = *(const bf16x8*)&vt16[((size_t)bh * 64 + r1) * Sn + jv];
    };
    auto swrite = [&](int buf) {
        *(bf16x8*)&Kt[buf][(wv * 16 + sr) * PAD + sc * 8]     = kreg0;
        *(bf16x8*)&Kt[buf][(wv * 16 + 8 + sr) * PAD + sc * 8] = kreg1;
        *(bf16x8*)&Vt[buf][(wv * 16 + sr) * PAD + sc * 8]     = vreg0;
        *(bf16x8*)&Vt[buf][(wv * 16 + 8 + sr) * PAD + sc * 8] = vreg1;
    };

    f32x4 acc_o[4][4] = {};
    float lrun[4] = {0.f, 0.f, 0.f, 0.f};
    __bf16* Pw = &Pt[wv][0];

    gload(0);
    swrite(0);
    __syncthreads();

    for (int st = 0; st < 12; st++) {
        const int buf = st & 1;
        if (st + 1 < 12) gload(st + 1);   // issue next global loads early

        if (st >= wv && st <= wv + 8) {
            const __bf16* KtB = &Kt[buf][0];
            const __bf16* VtB = &Vt[buf][0];
            // ---- S^T = K.Q^T, softmax, P -> LDS [query][key] ----
#pragma unroll
            for (int ti = 0; ti < 4; ti++) {
                bf16x8 ak0 = *(const bf16x8*)&KtB[(16 * ti + mrow) * PAD + quad * 8];
                bf16x8 ak1 = *(const bf16x8*)&KtB[(16 * ti + mrow) * PAD + 32 + quad * 8];
                const int y0 = 64 * st + 16 * ti + 4 * quad;
                f32x4 ms4 = *(const f32x4*)&Msh[y0];
#pragma unroll
                for (int tjq = 0; tjq < 4; tjq++) {
                    f32x4 s = {};
                    s = __builtin_amdgcn_mfma_f32_16x16x32_bf16(ak0, qf[tjq][0], s, 0, 0, 0);
                    s = __builtin_amdgcn_mfma_f32_16x16x32_bf16(ak1, qf[tjq][1], s, 0, 0, 0);
                    const int xq = 64 * wv + 16 * tjq + mrow;
                    bf16x4 pk;
                    float psum = 0.f;
#pragma unroll
                    for (int r = 0; r < 4; r++) {
                        const int y = y0 + r;
                        bool ok = ((unsigned)(y - xq) <= 512u) &
                                  ((unsigned)(jwin0 + y) < 4096u);
                        float pv = ok ? __expf(s[r] + ms4[r]) : 0.f;
                        psum += pv;
                        pk[r] = (__bf16)pv;
                    }
                    lrun[tjq] += psum;
                    *(bf16x4*)&Pw[(16 * tjq + mrow) * PAD + 16 * ti + 4 * quad] = pk;
                }
            }
            // ---- O^T += V^T.P^T ----
#pragma unroll
            for (int kc2 = 0; kc2 < 2; kc2++) {
                bf16x8 av[4];
#pragma unroll
                for (int dt = 0; dt < 4; dt++)
                    av[dt] = *(const bf16x8*)&VtB[(16 * dt + mrow) * PAD + kc2 * 32 + quad * 8];
#pragma unroll
                for (int tjq = 0; tjq < 4; tjq++) {
                    bf16x8 pf = *(const bf16x8*)&Pw[(16 * tjq + mrow) * PAD + kc2 * 32 + quad * 8];
#pragma unroll
                    for (int dt = 0; dt < 4; dt++)
                        acc_o[dt][tjq] = __builtin_amdgcn_mfma_f32_16x16x32_bf16(
                            av[dt], pf, acc_o[dt][tjq], 0, 0, 0);
                }
            }
        }

        if (st + 1 < 12) {
            swrite((st + 1) & 1);
            __syncthreads();
        }
    }

    // denominators: sum across quads (keys live across lane bits 4-5)
    float inv[4];
#pragma unroll
    for (int tjq = 0; tjq < 4; tjq++) {
        float l = lrun[tjq];
        l += __shfl_xor(l, 16);
        l += __shfl_xor(l, 32);
        inv[tjq] = 1.0f / l;
    }
    // O^T C-layout: row = d = 16*dt + 4*quad + r, col = q = mrow
#pragma unroll
    for (int dt = 0; dt < 4; dt++)
#pragma unroll
        for (int tjq = 0; tjq < 4; tjq++) {
            f32x4 o = acc_o[dt][tjq];
            o[0] *= inv[tjq]; o[1] *= inv[tjq]; o[2] *= inv[tjq]; o[3] *= inv[tjq];
            float* dst = out + ((size_t)(b * Sn + i0 + wv * 64 + 16 * tjq + mrow)) * En
                             + h * 64 + 16 * dt + 4 * quad;
            *(f32x4*)dst = o;
        }
}

extern "C" void kernel_launch(void* const* d_in, const int* in_sizes, int n_in,
                              void* d_out, int out_size, void* d_ws, size_t ws_size,
                              hipStream_t stream) {
    const float* hs  = (const float*)d_in[0];
    const int*  mask = (const int*)d_in[1];
    const float* qw  = (const float*)d_in[2];
    const float* qb  = (const float*)d_in[3];
    const float* kw  = (const float*)d_in[4];
    const float* kb  = (const float*)d_in[5];
    const float* vw  = (const float*)d_in[6];
    const float* vb  = (const float*)d_in[7];
    float* out = (float*)d_out;

    // Workspace: hs16 16.8MB | w16 6.3MB | q16 16.8MB | k16 16.8MB | vt16 16.8MB
    _Float16* hs16 = (_Float16*)d_ws;
    _Float16* w16  = (_Float16*)((char*)d_ws + (size_t)16777216);
    __bf16*   q16  = (__bf16*)((char*)d_ws + (size_t)23068672);
    __bf16*   k16  = (__bf16*)((char*)d_ws + (size_t)39845888);
    __bf16*   vt16 = (__bf16*)((char*)d_ws + (size_t)56623104);

    cvt_hs_kernel<<<8192, 256, 0, stream>>>(hs, hs16);
    cvt_w_kernel <<<3072, 256, 0, stream>>>(qw, kw, vw, w16);

    dim3 pgrid(Mtot / 128, 3072 / 128);   // (64, 24)
    qkv_mfma_kernel<<<pgrid, 256, 0, stream>>>(hs16, w16, qb, kb, vb, q16, k16, vt16);

    dim3 agrid(Sn / 256, Hn, Bn);         // (16, 16, 2)
    banded_attn_kernel<<<agrid, 256, 0, stream>>>(q16, k16, vt16, mask, out);
}

// Round 2
// 221.093 us; speedup vs baseline: 1.0603x; 1.0603x over previous
//
#include <hip/hip_runtime.h>
#include <math.h>

// Problem constants
constexpr int Bn  = 2;
constexpr int Sn  = 4096;
constexpr int En  = 1024;
constexpr int Hn  = 16;
constexpr int Mtot = Bn * Sn;             // 8192
constexpr int Kp  = 1024;                 // GEMM K (fp16 single precision)
constexpr int PAD = 72;                   // LDS row stride (bf16), 144 B = 9x16B

typedef __bf16    bf16x8 __attribute__((ext_vector_type(8)));
typedef __bf16    bf16x4 __attribute__((ext_vector_type(4)));
typedef _Float16  f16x8  __attribute__((ext_vector_type(8)));
typedef _Float16  f16x4  __attribute__((ext_vector_type(4)));
typedef float     f32x4  __attribute__((ext_vector_type(4)));

// ---------------- fp32 -> fp16 conversion ----------------
__global__ void __launch_bounds__(256)
cvt_hs_kernel(const float* __restrict__ hs, _Float16* __restrict__ hs16)
{
    int t = blockIdx.x * 256 + threadIdx.x;
    int m = t >> 8;
    int k = (t & 255) << 2;
    float4 x = *(const float4*)&hs[((size_t)m << 10) + k];
    f16x4 h;
    h[0] = (_Float16)x.x; h[1] = (_Float16)x.y;
    h[2] = (_Float16)x.z; h[3] = (_Float16)x.w;
    *(f16x4*)&hs16[((size_t)m << 10) + k] = h;
}

__global__ void __launch_bounds__(256)
cvt_w_kernel(const float* __restrict__ qw, const float* __restrict__ kw,
             const float* __restrict__ vw, _Float16* __restrict__ w16)
{
    int t = blockIdx.x * 256 + threadIdx.x;
    int gn = t >> 8;
    int k  = (t & 255) << 2;
    int p  = gn >> 10, n = gn & 1023;
    const float* src = (p == 0) ? qw : (p == 1) ? kw : vw;
    float4 x = *(const float4*)&src[((size_t)n << 10) + k];
    f16x4 h;
    h[0] = (_Float16)x.x; h[1] = (_Float16)x.y;
    h[2] = (_Float16)x.z; h[3] = (_Float16)x.w;
    *(f16x4*)&w16[((size_t)gn << 10) + k] = h;
}

// ---------------- QKV projection: fp16 MFMA GEMM ----------------------------
// A = hs16 (m = seq), B = w16 (n = feature, 3072 rows = q|k|v).
// v3: r0's single-buffer 2-barrier structure (m97 reference, occupancy ~31%)
//     + r1's two verified wins:
//       - XOR bank-conflict swizzle (chunk ^= (row>>1)&3), applied on the
//         pre-swizzled GLOBAL source at staging + on the ds_read address
//       - swapped-operand MFMA for q/k so the accumulator row dim is the
//         FEATURE dim -> contiguous bf16x4 epilogue stores
//     The q|k vs v operand orders are split at DISPATCH (template<PM>) so
//     each instantiation has one MFMA ladder (r1's dual-path loop cost
//     VGPR 76->124 / SGPR 32->112 and 11 pts of occupancy).
__device__ inline void load_lds16(const void* g, void* s) {
    __builtin_amdgcn_global_load_lds((const __attribute__((address_space(1))) void*)g,
                                     (__attribute__((address_space(3))) void*)s,
                                     16, 0, 0);
}

template<int PM>   // 0 = q|k (swapped operands), 1 = v
__global__ void __launch_bounds__(256)
qkv_mfma_kernel(const _Float16* __restrict__ A2, const _Float16* __restrict__ B2,
                const float* __restrict__ qb, const float* __restrict__ kb,
                const float* __restrict__ vb,
                __bf16* __restrict__ q16, __bf16* __restrict__ k16,
                __bf16* __restrict__ vt16, int n0base)
{
    __shared__ _Float16 As[128 * 32];
    __shared__ _Float16 Bs[128 * 32];

    const int tid  = threadIdx.x;
    const int m0   = blockIdx.x * 128;             // seq tile
    const int n0   = n0base + blockIdx.y * 128;    // feature tile
    const int w    = tid >> 6;
    const int lane = tid & 63;
    const int wm   = w >> 1, wn = w & 1;
    const int mrow = lane & 15, quad = lane >> 4;

    // staging: row = w*16 + (lane>>2); LDS dest is linear (lane*16B), so the
    // swizzle goes into the per-lane GLOBAL chunk: c_load = (lane&3) ^ f(row),
    // f(row) = (row>>1)&3 = (lane>>3)&3
    const int stRow = w * 16 + (lane >> 2);
    const int stCol = ((lane & 3) ^ ((lane >> 3) & 3)) * 8;
    // read swizzle: LDS slot (row, c) holds global chunk c ^ ((row>>1)&3)
    const int rq = (quad ^ ((mrow >> 1) & 3)) * 8;

    f32x4 acc[4][4] = {};

    const _Float16* Abase = A2 + (size_t)(m0 + stRow) * Kp + stCol;
    const _Float16* Bbase = B2 + (size_t)(n0 + stRow) * Kp + stCol;
    _Float16* AsW = &As[w * 512];
    _Float16* BsW = &Bs[w * 512];

    for (int k0 = 0; k0 < Kp; k0 += 32) {
        load_lds16(Abase + k0,            AsW);
        load_lds16(Abase + 64 * Kp + k0,  AsW + 2048);
        load_lds16(Bbase + k0,            BsW);
        load_lds16(Bbase + 64 * Kp + k0,  BsW + 2048);
        __syncthreads();
        f16x8 af[4], bfr[4];
#pragma unroll
        for (int t = 0; t < 4; t++) {
            af[t]  = *(const f16x8*)&As[(wm * 64 + t * 16 + mrow) * 32 + rq];
            bfr[t] = *(const f16x8*)&Bs[(wn * 64 + t * 16 + mrow) * 32 + rq];
        }
#pragma unroll
        for (int ti = 0; ti < 4; ti++)
#pragma unroll
            for (int tj = 0; tj < 4; tj++) {
                if (PM == 0)   // C[m=feature][n=seq]
                    acc[ti][tj] = __builtin_amdgcn_mfma_f32_16x16x32_f16(
                        bfr[tj], af[ti], acc[ti][tj], 0, 0, 0);
                else           // C[m=seq][n=feature]
                    acc[ti][tj] = __builtin_amdgcn_mfma_f32_16x16x32_f16(
                        af[ti], bfr[tj], acc[ti][tj], 0, 0, 0);
            }
        __syncthreads();
    }

    if (PM == 0) {
        // acc[ti][tj]: row (quad*4+r) = feature, col (mrow) = seq
        const int p = n0 >> 10;                    // 0=q, 1=k
        const float* bptr = (p == 0) ? qb : kb;
        __bf16* dst = (p == 0) ? q16 : k16;
        const float scl = (p == 0) ? 0.125f : 1.0f;
#pragma unroll
        for (int ti = 0; ti < 4; ti++) {
            const int m  = m0 + wm * 64 + ti * 16 + mrow;   // seq
            const int bb = m >> 12, ss = m & 4095;
#pragma unroll
            for (int tj = 0; tj < 4; tj++) {
                const int fl = (n0 + wn * 64 + tj * 16 + quad * 4) & 1023;
                const int hh = fl >> 6, dd = fl & 63;       // dd..dd+3
                const float4 bv = *(const float4*)&bptr[fl];
                bf16x4 o;
                o[0] = (__bf16)((acc[ti][tj][0] + bv.x) * scl);
                o[1] = (__bf16)((acc[ti][tj][1] + bv.y) * scl);
                o[2] = (__bf16)((acc[ti][tj][2] + bv.z) * scl);
                o[3] = (__bf16)((acc[ti][tj][3] + bv.w) * scl);
                *(bf16x4*)&dst[((size_t)(bb * Hn + hh) * Sn + ss) * 64 + dd] = o;
            }
        }
    } else {
        // acc[ti][tj]: row (quad*4+r) = seq, col (mrow) = feature; V^T layout
#pragma unroll
        for (int tj = 0; tj < 4; tj++) {
            const int n  = n0 + wn * 64 + tj * 16 + mrow;
            const float bv = vb[n & 1023];
            const int hh = (n & 1023) >> 6, dd = n & 63;
#pragma unroll
            for (int ti = 0; ti < 4; ti++) {
                const int m  = m0 + wm * 64 + ti * 16 + quad * 4;   // + r
                const int bb = m >> 12, ss = m & 4095;
                bf16x4 pv4;
#pragma unroll
                for (int r = 0; r < 4; r++)
                    pv4[r] = (__bf16)(acc[ti][tj][r] + bv);
                *(bf16x4*)&vt16[((size_t)(bb * Hn + hh) * 64 + dd) * Sn + ss] = pv4;
            }
        }
    }
}

// ---------------- Banded attention: MFMA, double-buffered staging -----------
// Block = 256 queries (4 waves x 64). S^T = K.Q^T ; O^T = V^T.P^T.
// ONE barrier per subtile: compute reads buf[st&1] while regs hold st+1 data;
// writes go to buf[(st+1)&1], whose last readers synced at the st-1 barrier.
__global__ void __launch_bounds__(256, 2)
banded_attn_kernel(const __bf16* __restrict__ q16, const __bf16* __restrict__ k16,
                   const __bf16* __restrict__ vt16, const int* __restrict__ mask,
                   float* __restrict__ out)
{
    __shared__ __bf16 Kt[2][64 * PAD];
    __shared__ __bf16 Vt[2][64 * PAD];
    __shared__ __bf16 Pt[4][64 * PAD];
    __shared__ float  Msh[768];

    const int c = blockIdx.x, h = blockIdx.y, b = blockIdx.z;
    const int bh = b * Hn + h;
    const int i0 = c * 256;
    const int jwin0 = i0 - 256;
    const int tid  = threadIdx.x;
    const int wv   = tid >> 6;
    const int lane = tid & 63;
    const int quad = lane >> 4, mrow = lane & 15;

#pragma unroll
    for (int rep = 0; rep < 3; rep++) {
        int idx = rep * 256 + tid;
        int jg  = jwin0 + idx;
        float mv = 0.f;
        if (jg >= 0 && jg < Sn && mask[b * Sn + jg] != 0) mv = -10000.f;
        Msh[idx] = mv;
    }

    // Q B-fragments (loop-invariant): B[k=d][n=q]
    bf16x8 qf[4][2];
    const __bf16* qbase = q16 + (((size_t)bh * Sn + i0 + wv * 64) << 6);
#pragma unroll
    for (int tjq = 0; tjq < 4; tjq++)
#pragma unroll
        for (int kc = 0; kc < 2; kc++)
            qf[tjq][kc] = *(const bf16x8*)(qbase + (16 * tjq + mrow) * 64 + 32 * kc + 8 * quad);

    const int sr = lane >> 3;      // 0..7
    const int sc = lane & 7;       // 16B chunk
    bf16x8 kreg0, kreg1, vreg0, vreg1;
    auto gload = [&](int st) {
        const int j0 = jwin0 + st * 64;
        const int r0 = wv * 16 + sr;
        const int r1 = wv * 16 + 8 + sr;
        int jk0 = j0 + r0; jk0 = jk0 < 0 ? 0 : (jk0 > Sn - 1 ? Sn - 1 : jk0);
        int jk1 = j0 + r1; jk1 = jk1 < 0 ? 0 : (jk1 > Sn - 1 ? Sn - 1 : jk1);
        kreg0 = *(const bf16x8*)&k16[(((size_t)bh * Sn + jk0) << 6) + sc * 8];
        kreg1 = *(const bf16x8*)&k16[(((size_t)bh * Sn + jk1) << 6) + sc * 8];
        int jv = j0 + sc * 8; jv = jv < 0 ? 0 : (jv > Sn - 8 ? Sn - 8 : jv);
        vreg0 = *(const bf16x8*)&vt16[((size_t)bh * 64 + r0) * Sn + jv];
        vreg1 = *(const bf16x8*)&vt16[((size_t)bh * 64 + r1) * Sn + jv];
    };
    auto swrite = [&](int buf) {
        *(bf16x8*)&Kt[buf][(wv * 16 + sr) * PAD + sc * 8]     = kreg0;
        *(bf16x8*)&Kt[buf][(wv * 16 + 8 + sr) * PAD + sc * 8] = kreg1;
        *(bf16x8*)&Vt[buf][(wv * 16 + sr) * PAD + sc * 8]     = vreg0;
        *(bf16x8*)&Vt[buf][(wv * 16 + 8 + sr) * PAD + sc * 8] = vreg1;
    };

    f32x4 acc_o[4][4] = {};
    float lrun[4] = {0.f, 0.f, 0.f, 0.f};
    __bf16* Pw = &Pt[wv][0];

    gload(0);
    swrite(0);
    __syncthreads();

    for (int st = 0; st < 12; st++) {
        const int buf = st & 1;
        if (st + 1 < 12) gload(st + 1);   // issue next global loads early

        if (st >= wv && st <= wv + 8) {
            const __bf16* KtB = &Kt[buf][0];
            const __bf16* VtB = &Vt[buf][0];
            // ---- S^T = K.Q^T, softmax, P -> LDS [query][key] ----
#pragma unroll
            for (int ti = 0; ti < 4; ti++) {
                bf16x8 ak0 = *(const bf16x8*)&KtB[(16 * ti + mrow) * PAD + quad * 8];
                bf16x8 ak1 = *(const bf16x8*)&KtB[(16 * ti + mrow) * PAD + 32 + quad * 8];
                const int y0 = 64 * st + 16 * ti + 4 * quad;
                f32x4 ms4 = *(const f32x4*)&Msh[y0];
#pragma unroll
                for (int tjq = 0; tjq < 4; tjq++) {
                    f32x4 s = {};
                    s = __builtin_amdgcn_mfma_f32_16x16x32_bf16(ak0, qf[tjq][0], s, 0, 0, 0);
                    s = __builtin_amdgcn_mfma_f32_16x16x32_bf16(ak1, qf[tjq][1], s, 0, 0, 0);
                    const int xq = 64 * wv + 16 * tjq + mrow;
                    bf16x4 pk;
                    float psum = 0.f;
#pragma unroll
                    for (int r = 0; r < 4; r++) {
                        const int y = y0 + r;
                        bool ok = ((unsigned)(y - xq) <= 512u) &
                                  ((unsigned)(jwin0 + y) < 4096u);
                        float pv = ok ? __expf(s[r] + ms4[r]) : 0.f;
                        psum += pv;
                        pk[r] = (__bf16)pv;
                    }
                    lrun[tjq] += psum;
                    *(bf16x4*)&Pw[(16 * tjq + mrow) * PAD + 16 * ti + 4 * quad] = pk;
                }
            }
            // ---- O^T += V^T.P^T ----
#pragma unroll
            for (int kc2 = 0; kc2 < 2; kc2++) {
                bf16x8 av[4];
#pragma unroll
                for (int dt = 0; dt < 4; dt++)
                    av[dt] = *(const bf16x8*)&VtB[(16 * dt + mrow) * PAD + kc2 * 32 + quad * 8];
#pragma unroll
                for (int tjq = 0; tjq < 4; tjq++) {
                    bf16x8 pf = *(const bf16x8*)&Pw[(16 * tjq + mrow) * PAD + kc2 * 32 + quad * 8];
#pragma unroll
                    for (int dt = 0; dt < 4; dt++)
                        acc_o[dt][tjq] = __builtin_amdgcn_mfma_f32_16x16x32_bf16(
                            av[dt], pf, acc_o[dt][tjq], 0, 0, 0);
                }
            }
        }

        if (st + 1 < 12) {
            swrite((st + 1) & 1);
            __syncthreads();
        }
    }

    // denominators: sum across quads (keys live across lane bits 4-5)
    float inv[4];
#pragma unroll
    for (int tjq = 0; tjq < 4; tjq++) {
        float l = lrun[tjq];
        l += __shfl_xor(l, 16);
        l += __shfl_xor(l, 32);
        inv[tjq] = 1.0f / l;
    }
    // O^T C-layout: row = d = 16*dt + 4*quad + r, col = q = mrow
#pragma unroll
    for (int dt = 0; dt < 4; dt++)
#pragma unroll
        for (int tjq = 0; tjq < 4; tjq++) {
            f32x4 o = acc_o[dt][tjq];
            o[0] *= inv[tjq]; o[1] *= inv[tjq]; o[2] *= inv[tjq]; o[3] *= inv[tjq];
            float* dst = out + ((size_t)(b * Sn + i0 + wv * 64 + 16 * tjq + mrow)) * En
                             + h * 64 + 16 * dt + 4 * quad;
            *(f32x4*)dst = o;
        }
}

extern "C" void kernel_launch(void* const* d_in, const int* in_sizes, int n_in,
                              void* d_out, int out_size, void* d_ws, size_t ws_size,
                              hipStream_t stream) {
    const float* hs  = (const float*)d_in[0];
    const int*  mask = (const int*)d_in[1];
    const float* qw  = (const float*)d_in[2];
    const float* qb  = (const float*)d_in[3];
    const float* kw  = (const float*)d_in[4];
    const float* kb  = (const float*)d_in[5];
    const float* vw  = (const float*)d_in[6];
    const float* vb  = (const float*)d_in[7];
    float* out = (float*)d_out;

    // Workspace: hs16 16.8MB | w16 6.3MB | q16 16.8MB | k16 16.8MB | vt16 16.8MB
    _Float16* hs16 = (_Float16*)d_ws;
    _Float16* w16  = (_Float16*)((char*)d_ws + (size_t)16777216);
    __bf16*   q16  = (__bf16*)((char*)d_ws + (size_t)23068672);
    __bf16*   k16  = (__bf16*)((char*)d_ws + (size_t)39845888);
    __bf16*   vt16 = (__bf16*)((char*)d_ws + (size_t)56623104);

    cvt_hs_kernel<<<8192, 256, 0, stream>>>(hs, hs16);
    cvt_w_kernel <<<3072, 256, 0, stream>>>(qw, kw, vw, w16);

    dim3 pgridQK(Mtot / 128, 2048 / 128);   // (64, 16): q|k features
    qkv_mfma_kernel<0><<<pgridQK, 256, 0, stream>>>(hs16, w16, qb, kb, vb,
                                                    q16, k16, vt16, 0);
    dim3 pgridV(Mtot / 128, 1024 / 128);    // (64, 8): v features
    qkv_mfma_kernel<1><<<pgridV, 256, 0, stream>>>(hs16, w16, qb, kb, vb,
                                                   q16, k16, vt16, 2048);

    dim3 agrid(Sn / 256, Hn, Bn);           // (16, 16, 2)
    banded_attn_kernel<<<agrid, 256, 0, stream>>>(q16, k16, vt16, mask, out);
}